// Round 16
// baseline (423.281 us; speedup 1.0000x reference)
//
#include <hip/hip_runtime.h>
#include <stdint.h>

// GraphConv x5 on MI355X — round 16 (= round 15 with the NT-store compile
// fix: int2 packed into uint64_t for __builtin_nontemporal_store).
// (1) Non-temporal hints on all STREAMING traffic in the fused kernel
//     (pairs window, Rb prefetch, G/R write-out) and bpart streams — keeps
//     the 4MB/XCD L2 dedicated to the randomly-gathered 12.8MB Gb table.
// (2) k_l0pre aggregation parallelized: all 4 waves, edge-parallel lanes +
//     shfl reduction.

#define NN 100000
#define NE 1600000
#define HID 64
#define NBKT 391            // ceil(NN/256), bucket = dst >> 8
#define CAP 8192            // padded bucket capacity (mean 4092, +64 sigma)
#define TILE 4096
#define EPT 16              // TILE / 256
#define NTILE ((NE + TILE - 1) / TILE)   // 391

typedef __attribute__((ext_vector_type(8))) short bf16x8;
typedef __attribute__((ext_vector_type(4))) float f32x4;

__device__ __forceinline__ uint32_t rne_bf16(float v) {
    uint32_t u = __float_as_uint(v);
    return (u + 0x7fffu + ((u >> 16) & 1u)) >> 16;
}

// ---------------- CSR build ----------------

__global__ __launch_bounds__(256) void k_bpart(const int* __restrict__ src,
                                               const int* __restrict__ dst,
                                               const float* __restrict__ w,
                                               int* __restrict__ bcur,
                                               uint64_t* __restrict__ bpairs) {
    __shared__ int hcnt[NBKT];
    __shared__ int hbase[NBKT];
    int tile0 = blockIdx.x * TILE;
    for (int t = threadIdx.x; t < NBKT; t += 256) hcnt[t] = 0;
    __syncthreads();

    int   pk[EPT];
    int   bk[EPT];
    float wv[EPT];
    #pragma unroll
    for (int k = 0; k < EPT; k++) {
        int e = tile0 + threadIdx.x + k * 256;
        if (e < NE) {
            int d = __builtin_nontemporal_load(&dst[e]);
            int b = d >> 8;
            pk[k] = (__builtin_nontemporal_load(&src[e]) << 8) | (d & 255);
            wv[k] = __builtin_nontemporal_load(&w[e]);
            bk[k] = b;
            atomicAdd(&hcnt[b], 1);
        } else {
            bk[k] = -1;
        }
    }
    __syncthreads();
    for (int t = threadIdx.x; t < NBKT; t += 256) {
        int c = hcnt[t];
        hbase[t] = c ? atomicAdd(&bcur[t], c) : 0;
        hcnt[t] = 0;
    }
    __syncthreads();
    #pragma unroll
    for (int k = 0; k < EPT; k++) {
        if (bk[k] >= 0) {
            int pos = hbase[bk[k]] + atomicAdd(&hcnt[bk[k]], 1);
            uint64_t rec = (uint64_t)(uint32_t)pk[k]
                         | ((uint64_t)(uint32_t)__float_as_int(wv[k]) << 32);
            __builtin_nontemporal_store(rec, &bpairs[pos]);
        }
    }
}

__global__ __launch_bounds__(256) void k_bcsr(const int* __restrict__ bcur,
                                              const uint64_t* __restrict__ bpairs,
                                              int* __restrict__ offs,
                                              int* __restrict__ ends,
                                              uint32_t* __restrict__ pairs) {
    __shared__ int cnt[256];
    __shared__ int scn[256];
    __shared__ int cur[256];
    int k = blockIdx.x, t = threadIdx.x;
    int base = k * CAP;
    int scnt = bcur[k] - base;
    cnt[t] = 0;
    __syncthreads();
    for (int j = t; j < scnt; j += 256)
        atomicAdd(&cnt[(int)(bpairs[base + j] & 255u)], 1);
    __syncthreads();
    int v = cnt[t], acc = v;
    scn[t] = v;
    __syncthreads();
    for (int off = 1; off < 256; off <<= 1) {
        int u = (t >= off) ? scn[t - off] : 0;
        __syncthreads();
        acc += u;
        scn[t] = acc;
        __syncthreads();
    }
    int excl = acc - v;
    cur[t] = excl;
    int d = (k << 8) + t;
    if (d < NN) {
        offs[d] = base + excl;
        ends[d] = base + excl + v;
    }
    __syncthreads();
    for (int j = t; j < scnt; j += 256) {
        uint64_t q = bpairs[base + j];
        uint32_t lo = (uint32_t)q;
        float wf = __uint_as_float((uint32_t)(q >> 32));
        int pos = base + atomicAdd(&cur[(int)(lo & 255u)], 1);
        uint32_t wb = rne_bf16(wf) & 0x7fffu;   // w >= 0
        __builtin_nontemporal_store((wb << 17) | (lo >> 8), &pairs[pos]);
    }
}

// ---------------- weight hi/lo split (+ bucket cursor init) ----------------

__global__ __launch_bounds__(256) void k_wsplit(const float* __restrict__ Wrel_mid,
                                                const float* __restrict__ Wroot_mid,
                                                uint16_t* __restrict__ WgH,
                                                uint16_t* __restrict__ WgL,
                                                uint16_t* __restrict__ WrH,
                                                uint16_t* __restrict__ WrL,
                                                int* __restrict__ bcur) {
    int i = blockIdx.x * blockDim.x + threadIdx.x;
    if (i < NBKT) bcur[i] = i * CAP;
    if (i >= 3 * 4096) return;
    float a = Wrel_mid[i];
    uint32_t ah = rne_bf16(a);
    float al = a - __uint_as_float(ah << 16);
    WgH[i] = (uint16_t)ah;
    WgL[i] = (uint16_t)rne_bf16(al);
    float b = Wroot_mid[i];
    uint32_t bh = rne_bf16(b);
    float bl = b - __uint_as_float(bh << 16);
    WrH[i] = (uint16_t)bh;
    WrL[i] = (uint16_t)rne_bf16(bl);
}

// ---------------- shared epilogue: 16-node h (LDS) -> G,R via LDS tiles ----

__device__ __forceinline__ void mfma_epilogue(
        int lane, int w, const uint32_t* sH,
        const uint16_t* __restrict__ WgH, const uint16_t* __restrict__ WgL,
        const uint16_t* __restrict__ WrH, const uint16_t* __restrict__ WrL,
        const float* __restrict__ brel,
        uint16_t* sG, uint16_t* sR) {
    int row = lane & 15;
    int quad = lane >> 4;
    int kb = quad * 8;
    bf16x8 ah0 = *(const bf16x8*)&sH[row * 36 + quad * 4];
    bf16x8 ah1 = *(const bf16x8*)&sH[row * 36 + 16 + quad * 4];
    int oc = w * 16 + row;
    {
        bf16x8 bh0 = *(const bf16x8*)&WgH[oc * 64 + kb];
        bf16x8 bh1 = *(const bf16x8*)&WgH[oc * 64 + 32 + kb];
        bf16x8 bl0 = *(const bf16x8*)&WgL[oc * 64 + kb];
        bf16x8 bl1 = *(const bf16x8*)&WgL[oc * 64 + 32 + kb];
        f32x4 acc = {0.f, 0.f, 0.f, 0.f};
        acc = __builtin_amdgcn_mfma_f32_16x16x32_bf16(ah0, bh0, acc, 0, 0, 0);
        acc = __builtin_amdgcn_mfma_f32_16x16x32_bf16(ah1, bh1, acc, 0, 0, 0);
        acc = __builtin_amdgcn_mfma_f32_16x16x32_bf16(ah0, bl0, acc, 0, 0, 0);
        acc = __builtin_amdgcn_mfma_f32_16x16x32_bf16(ah1, bl1, acc, 0, 0, 0);
        #pragma unroll
        for (int r = 0; r < 4; r++)
            sG[(quad * 4 + r) * 68 + oc] = (uint16_t)rne_bf16(acc[r]);
    }
    {
        bf16x8 bh0 = *(const bf16x8*)&WrH[oc * 64 + kb];
        bf16x8 bh1 = *(const bf16x8*)&WrH[oc * 64 + 32 + kb];
        bf16x8 bl0 = *(const bf16x8*)&WrL[oc * 64 + kb];
        bf16x8 bl1 = *(const bf16x8*)&WrL[oc * 64 + 32 + kb];
        float bias = brel[oc];
        f32x4 acc = {bias, bias, bias, bias};
        acc = __builtin_amdgcn_mfma_f32_16x16x32_bf16(ah0, bh0, acc, 0, 0, 0);
        acc = __builtin_amdgcn_mfma_f32_16x16x32_bf16(ah1, bh1, acc, 0, 0, 0);
        acc = __builtin_amdgcn_mfma_f32_16x16x32_bf16(ah0, bl0, acc, 0, 0, 0);
        acc = __builtin_amdgcn_mfma_f32_16x16x32_bf16(ah1, bl1, acc, 0, 0, 0);
        #pragma unroll
        for (int r = 0; r < 4; r++)
            sR[(quad * 4 + r) * 68 + oc] = (uint16_t)rne_bf16(acc[r]);
    }
}

__device__ __forceinline__ void epilogue_writeout(
        int tid, int blk16, const uint16_t* sG, const uint16_t* sR,
        uint16_t* __restrict__ Gout, uint16_t* __restrict__ Rout) {
    const uint32_t* sGd = (const uint32_t*)sG;   // stride 34 dwords/node
    const uint32_t* sRd = (const uint32_t*)sR;
    uint32_t* Gd = (uint32_t*)Gout;
    uint32_t* Rd = (uint32_t*)Rout;
    #pragma unroll
    for (int it = 0; it < 2; it++) {
        int idx = it * 256 + tid;
        int nd = idx >> 5, col = idx & 31;
        __builtin_nontemporal_store(sGd[nd * 34 + col], &Gd[(blk16 + nd) * 32 + col]);
        __builtin_nontemporal_store(sRd[nd * 34 + col], &Rd[(blk16 + nd) * 32 + col]);
    }
}

// ---------------- layers ----------------

// layer 0 (fused): edge-parallel aggregation (all waves, shfl reduce), then
// h0 = relu(...) staged in LDS, MFMA epilogue -> G1,R1.
__global__ __launch_bounds__(256) void k_l0pre(
        const int* __restrict__ offs, const int* __restrict__ ends,
        const uint32_t* __restrict__ pairs, const float* __restrict__ x,
        const float* __restrict__ Wrel0, const float* __restrict__ brel0,
        const float* __restrict__ Wroot0,
        const uint16_t* __restrict__ WgH, const uint16_t* __restrict__ WgL,
        const uint16_t* __restrict__ WrH, const uint16_t* __restrict__ WrL,
        const float* __restrict__ brel,
        uint16_t* __restrict__ Gout, uint16_t* __restrict__ Rout) {
    __shared__ uint32_t sH[16 * 36];
    __shared__ uint16_t sG[16 * 68];
    __shared__ uint16_t sR[16 * 68];
    int c = threadIdx.x & 63;
    int w = threadIdx.x >> 6;
    int blk16 = blockIdx.x * 16;
    float agg[4];
    #pragma unroll
    for (int t = 0; t < 4; t++) {
        int node = blk16 + w * 4 + t;
        int b = offs[node], e = ends[node];
        float pp = 0.f;
        for (int j = b + c; j < e; j += 64) {
            uint32_t r = __builtin_nontemporal_load(&pairs[j]);
            pp += __uint_as_float((r >> 17) << 16) * x[r & 0x1ffffu];
        }
        for (int o = 32; o > 0; o >>= 1) pp += __shfl_down(pp, o, 64);
        agg[t] = __shfl(pp, 0, 64);
    }
    float wr = Wrel0[c], br = brel0[c], wo = Wroot0[c];
    #pragma unroll
    for (int t = 0; t < 4; t++) {
        int node = blk16 + w * 4 + t;
        float v = agg[t] * wr + br + x[node] * wo;
        v = v > 0.f ? v : 0.f;
        uint32_t hb = rne_bf16(v);
        uint32_t pn = (uint32_t)__shfl_xor((int)hb, 1, 64);
        if (!(c & 1)) sH[(w * 4 + t) * 36 + (c >> 1)] = hb | (pn << 16);
    }
    __syncthreads();
    mfma_epilogue(c, w, sH, WgH, WgL, WrH, WrL, brel, sG, sR);
    __syncthreads();
    epilogue_writeout((int)threadIdx.x, blk16, sG, sR, Gout, Rout);
}

// Fused aggregation + pre-transform. Streaming traffic (pairs window, Rb,
// write-out) is non-temporal so L2 stays dedicated to the Gb gather table.
template <bool LAST>
__global__ __launch_bounds__(256, 4) void k_aggfused(
        const int* __restrict__ offs, const int* __restrict__ ends,
        const uint32_t* __restrict__ pairs,
        const uint16_t* __restrict__ Gb, const uint16_t* __restrict__ Rb,
        const uint16_t* __restrict__ WgH, const uint16_t* __restrict__ WgL,
        const uint16_t* __restrict__ WrH, const uint16_t* __restrict__ WrL,
        const float* __restrict__ brel,
        uint16_t* __restrict__ Gout, uint16_t* __restrict__ Rout,
        const float* __restrict__ WrelL, const float* __restrict__ WrootL,
        float* __restrict__ sarr, float* __restrict__ rarr) {
    __shared__ uint32_t sH[16 * 36];
    __shared__ uint16_t sG[16 * 68];
    __shared__ uint16_t sR[16 * 68];
    int c = threadIdx.x & 63;
    int w = threadIdx.x >> 6;
    int blk16 = blockIdx.x * 16;
    int n0 = blk16 + w * 4;
    int ov = 0;
    if (c < 4) ov = offs[n0 + c];
    else if (c == 4) ov = ends[n0 + 3];
    int bnd[5];
    bnd[0] = __builtin_amdgcn_readlane(ov, 0);
    bnd[1] = __builtin_amdgcn_readlane(ov, 1);
    bnd[2] = __builtin_amdgcn_readlane(ov, 2);
    bnd[3] = __builtin_amdgcn_readlane(ov, 3);
    bnd[4] = __builtin_amdgcn_readlane(ov, 4);

    // prefetch R rows (consumed only in the epilogue) — streaming, nt
    uint32_t ur[4];
    #pragma unroll
    for (int t = 0; t < 4; t++)
        ur[t] = __builtin_nontemporal_load(&Rb[(n0 + t) * 64 + c]);

    float acc[4][4];
    #pragma unroll
    for (int t = 0; t < 4; t++)
        #pragma unroll
        for (int q = 0; q < 4; q++) acc[t][q] = 0.f;

    for (int cb = bnd[0]; cb < bnd[4]; cb += 64) {
        int n = bnd[4] - cb; if (n > 64) n = 64;
        uint32_t p = (c < n) ? __builtin_nontemporal_load(&pairs[cb + c]) : 0u;
        #pragma unroll
        for (int t = 0; t < 4; t++) {
            int lo = bnd[t]     > cb     ? bnd[t]     : cb;
            int hi = bnd[t + 1] < cb + n ? bnd[t + 1] : cb + n;
            int j = lo;
            for (; j + 16 <= hi; j += 16) {
                int jj = j - cb;
                uint32_t rr[16], uu[16];
                #pragma unroll
                for (int q = 0; q < 16; q++)
                    rr[q] = __builtin_amdgcn_readlane(p, jj + q);
                #pragma unroll
                for (int q = 0; q < 16; q++)
                    uu[q] = Gb[(rr[q] & 0x1ffffu) * 64 + c];
                #pragma unroll
                for (int q = 0; q < 16; q++)
                    acc[t][q & 3] += __uint_as_float((rr[q] >> 17) << 16)
                                   * __uint_as_float(uu[q] << 16);
            }
            for (; j + 8 <= hi; j += 8) {
                int jj = j - cb;
                uint32_t rr[8], uu[8];
                #pragma unroll
                for (int q = 0; q < 8; q++)
                    rr[q] = __builtin_amdgcn_readlane(p, jj + q);
                #pragma unroll
                for (int q = 0; q < 8; q++)
                    uu[q] = Gb[(rr[q] & 0x1ffffu) * 64 + c];
                #pragma unroll
                for (int q = 0; q < 8; q++)
                    acc[t][q & 3] += __uint_as_float((rr[q] >> 17) << 16)
                                   * __uint_as_float(uu[q] << 16);
            }
            for (; j + 4 <= hi; j += 4) {
                int jj = j - cb;
                uint32_t rr[4], uu[4];
                #pragma unroll
                for (int q = 0; q < 4; q++)
                    rr[q] = __builtin_amdgcn_readlane(p, jj + q);
                #pragma unroll
                for (int q = 0; q < 4; q++)
                    uu[q] = Gb[(rr[q] & 0x1ffffu) * 64 + c];
                #pragma unroll
                for (int q = 0; q < 4; q++)
                    acc[t][q] += __uint_as_float((rr[q] >> 17) << 16)
                               * __uint_as_float(uu[q] << 16);
            }
            for (; j < hi; j++) {
                int jj = j - cb;
                uint32_t r = __builtin_amdgcn_readlane(p, jj);
                uint32_t u = Gb[(r & 0x1ffffu) * 64 + c];
                acc[t][0] += __uint_as_float((r >> 17) << 16)
                           * __uint_as_float(u << 16);
            }
        }
    }
    #pragma unroll
    for (int t = 0; t < 4; t++) {
        float v = (acc[t][0] + acc[t][1]) + (acc[t][2] + acc[t][3])
                + __uint_as_float(ur[t] << 16);
        v = v > 0.f ? v : 0.f;
        if (!LAST) {
            uint32_t hb = rne_bf16(v);
            uint32_t pn = (uint32_t)__shfl_xor((int)hb, 1, 64);
            if (!(c & 1)) sH[(w * 4 + t) * 36 + (c >> 1)] = hb | (pn << 16);
        } else {
            float a = v * WrelL[c];
            float r = v * WrootL[c];
            for (int o = 32; o > 0; o >>= 1) {
                a += __shfl_down(a, o, 64);
                r += __shfl_down(r, o, 64);
            }
            if (c == 0) { sarr[n0 + t] = a; rarr[n0 + t] = r; }
        }
    }
    if (!LAST) {
        __syncthreads();
        mfma_epilogue(c, w, sH, WgH, WgL, WrH, WrL, brel, sG, sR);
        __syncthreads();
        epilogue_writeout((int)threadIdx.x, blk16, sG, sR, Gout, Rout);
    }
}

__global__ void k_last(const int* __restrict__ offs, const int* __restrict__ ends,
                       const uint32_t* __restrict__ pairs,
                       const float* __restrict__ sarr, const float* __restrict__ rarr,
                       const float* __restrict__ brelL, float* __restrict__ out) {
    int i = blockIdx.x * blockDim.x + threadIdx.x;
    if (i >= NN) return;
    float a0 = rarr[i] + brelL[0], a1 = 0.f;
    int b = offs[i], e = ends[i];
    int j = b;
    for (; j + 2 <= e; j += 2) {
        uint32_t r0 = __builtin_nontemporal_load(&pairs[j]);
        uint32_t r1 = __builtin_nontemporal_load(&pairs[j + 1]);
        a0 += __uint_as_float((r0 >> 17) << 16) * sarr[r0 & 0x1ffffu];
        a1 += __uint_as_float((r1 >> 17) << 16) * sarr[r1 & 0x1ffffu];
    }
    for (; j < e; j++) {
        uint32_t r = __builtin_nontemporal_load(&pairs[j]);
        a0 += __uint_as_float((r >> 17) << 16) * sarr[r & 0x1ffffu];
    }
    out[i] = a0 + a1;
}

extern "C" void kernel_launch(void* const* d_in, const int* in_sizes, int n_in,
                              void* d_out, int out_size, void* d_ws, size_t ws_size,
                              hipStream_t stream) {
    const float* x        = (const float*)d_in[0];
    const int*   ei       = (const int*)d_in[1];
    const float* ew       = (const float*)d_in[2];
    const float* Wrel0    = (const float*)d_in[3];
    const float* brel0    = (const float*)d_in[4];
    const float* Wroot0   = (const float*)d_in[5];
    const float* Wrel_mid = (const float*)d_in[6];
    const float* brel_mid = (const float*)d_in[7];
    const float* Wroot_mid= (const float*)d_in[8];
    const float* WrelL    = (const float*)d_in[9];
    const float* brelL    = (const float*)d_in[10];
    const float* WrootL   = (const float*)d_in[11];
    float* out = (float*)d_out;

    const int* src  = ei;
    const int* dstp = ei + NE;

    char* w = (char*)d_ws;
    size_t o = 0;
    auto alloc = [&](size_t b) -> void* {
        void* r = (void*)(w + o);
        o += (b + 255) & ~(size_t)255;
        return r;
    };
    int*      offs  = (int*)alloc((size_t)NN * 4);
    int*      ends  = (int*)alloc((size_t)NN * 4);
    int*      bcur  = (int*)alloc((size_t)NBKT * 4);
    uint16_t* WgH   = (uint16_t*)alloc((size_t)3 * 4096 * 2);
    uint16_t* WgL   = (uint16_t*)alloc((size_t)3 * 4096 * 2);
    uint16_t* WrH   = (uint16_t*)alloc((size_t)3 * 4096 * 2);
    uint16_t* WrL   = (uint16_t*)alloc((size_t)3 * 4096 * 2);
    float*    sarr  = (float*)alloc((size_t)NN * 4);
    float*    rarr  = (float*)alloc((size_t)NN * 4);
    uint32_t* pairs = (uint32_t*)alloc((size_t)NBKT * CAP * 4);  // 12.8 MB padded
    uint16_t* GbA   = (uint16_t*)alloc((size_t)NN * HID * 2);    // 12.8 MB
    uint16_t* RbA   = (uint16_t*)alloc((size_t)NN * HID * 2);
    uint16_t* GbB   = (uint16_t*)alloc((size_t)NN * HID * 2);    // GbB/RbB contiguous
    uint16_t* RbB   = (uint16_t*)alloc((size_t)NN * HID * 2);
    (void)RbB;
    // bpairs (NBKT*CAP*8B = 25.6MB) aliases GbB+RbB (contiguous; dead before
    // mid layer 1 writes set B)
    uint64_t* bpairs = (uint64_t*)GbB;

    // weight split + bucket cursor init (one launch)
    k_wsplit<<<(3 * 4096 + 255) / 256, 256, 0, stream>>>(
        Wrel_mid, Wroot_mid, WgH, WgL, WrH, WrL, bcur);

    // CSR build (padded buckets)
    k_bpart<<<NTILE, 256, 0, stream>>>(src, dstp, ew, bcur, bpairs);
    k_bcsr<<<NBKT, 256, 0, stream>>>(bcur, bpairs, offs, ends, pairs);

    // layer 0 (agg + transform + pre) -> G1,R1 (set A)
    k_l0pre<<<NN / 16, 256, 0, stream>>>(
        offs, ends, pairs, x, Wrel0, brel0, Wroot0,
        WgH, WgL, WrH, WrL, brel_mid, GbA, RbA);

    // mid layer 1: consume set A, produce set B (weights index 1)
    k_aggfused<false><<<NN / 16, 256, 0, stream>>>(
        offs, ends, pairs, GbA, RbA,
        WgH + 4096, WgL + 4096, WrH + 4096, WrL + 4096, brel_mid + HID,
        GbB, RbB, WrelL, WrootL, sarr, rarr);
    // mid layer 2: consume set B, produce set A (weights index 2)
    k_aggfused<false><<<NN / 16, 256, 0, stream>>>(
        offs, ends, pairs, GbB, RbB,
        WgH + 2 * 4096, WgL + 2 * 4096, WrH + 2 * 4096, WrL + 2 * 4096,
        brel_mid + 2 * HID, GbA, RbA, WrelL, WrootL, sarr, rarr);
    // mid layer 3 (LAST): consume set A, produce s/r scalars
    k_aggfused<true><<<NN / 16, 256, 0, stream>>>(
        offs, ends, pairs, GbA, RbA,
        WgH, WgL, WrH, WrL, brel_mid,
        GbB, RbB, WrelL, WrootL, sarr, rarr);

    // final edge pass on scalars
    k_last<<<(NN + 255) / 256, 256, 0, stream>>>(offs, ends, pairs, sarr, rarr, brelL, out);
}

// Round 17
// 329.162 us; speedup vs baseline: 1.2859x; 1.2859x over previous
//
#include <hip/hip_runtime.h>
#include <stdint.h>

// GraphConv x5 on MI355X — round 17.
// vs round 16: full revert of the non-temporal experiment (NT stores broke
// L2 write-merging in bcsr: WRITE 13->118MB, 64us; NT on the pairs window
// also regressed aggfused 61->64us — the window IS block-reused). Keeps the
// round-15/16 k_l0pre parallelization (all-wave edge-parallel + shfl).
// Everything else = round-14 validated best (337.8us).

#define NN 100000
#define NE 1600000
#define HID 64
#define NBKT 391            // ceil(NN/256), bucket = dst >> 8
#define CAP 8192            // padded bucket capacity (mean 4092, +64 sigma)
#define TILE 4096
#define EPT 16              // TILE / 256
#define NTILE ((NE + TILE - 1) / TILE)   // 391

typedef __attribute__((ext_vector_type(8))) short bf16x8;
typedef __attribute__((ext_vector_type(4))) float f32x4;

__device__ __forceinline__ uint32_t rne_bf16(float v) {
    uint32_t u = __float_as_uint(v);
    return (u + 0x7fffu + ((u >> 16) & 1u)) >> 16;
}

// ---------------- CSR build ----------------

__global__ __launch_bounds__(256) void k_bpart(const int* __restrict__ src,
                                               const int* __restrict__ dst,
                                               const float* __restrict__ w,
                                               int* __restrict__ bcur,
                                               int2* __restrict__ bpairs) {
    __shared__ int hcnt[NBKT];
    __shared__ int hbase[NBKT];
    int tile0 = blockIdx.x * TILE;
    for (int t = threadIdx.x; t < NBKT; t += 256) hcnt[t] = 0;
    __syncthreads();

    int   pk[EPT];
    int   bk[EPT];
    float wv[EPT];
    #pragma unroll
    for (int k = 0; k < EPT; k++) {
        int e = tile0 + threadIdx.x + k * 256;
        if (e < NE) {
            int d = dst[e];
            int b = d >> 8;
            pk[k] = (src[e] << 8) | (d & 255);
            wv[k] = w[e];
            bk[k] = b;
            atomicAdd(&hcnt[b], 1);
        } else {
            bk[k] = -1;
        }
    }
    __syncthreads();
    for (int t = threadIdx.x; t < NBKT; t += 256) {
        int c = hcnt[t];
        hbase[t] = c ? atomicAdd(&bcur[t], c) : 0;
        hcnt[t] = 0;
    }
    __syncthreads();
    #pragma unroll
    for (int k = 0; k < EPT; k++) {
        if (bk[k] >= 0) {
            int pos = hbase[bk[k]] + atomicAdd(&hcnt[bk[k]], 1);
            bpairs[pos] = make_int2(pk[k], __float_as_int(wv[k]));
        }
    }
}

__global__ __launch_bounds__(256) void k_bcsr(const int* __restrict__ bcur,
                                              const int2* __restrict__ bpairs,
                                              int* __restrict__ offs,
                                              int* __restrict__ ends,
                                              uint32_t* __restrict__ pairs) {
    __shared__ int cnt[256];
    __shared__ int scn[256];
    __shared__ int cur[256];
    int k = blockIdx.x, t = threadIdx.x;
    int base = k * CAP;
    int scnt = bcur[k] - base;
    cnt[t] = 0;
    __syncthreads();
    for (int j = t; j < scnt; j += 256)
        atomicAdd(&cnt[bpairs[base + j].x & 255], 1);
    __syncthreads();
    int v = cnt[t], acc = v;
    scn[t] = v;
    __syncthreads();
    for (int off = 1; off < 256; off <<= 1) {
        int u = (t >= off) ? scn[t - off] : 0;
        __syncthreads();
        acc += u;
        scn[t] = acc;
        __syncthreads();
    }
    int excl = acc - v;
    cur[t] = excl;
    int d = (k << 8) + t;
    if (d < NN) {
        offs[d] = base + excl;
        ends[d] = base + excl + v;
    }
    __syncthreads();
    for (int j = t; j < scnt; j += 256) {
        int2 q = bpairs[base + j];
        int pos = base + atomicAdd(&cur[q.x & 255], 1);
        uint32_t wb = rne_bf16(__int_as_float(q.y)) & 0x7fffu;   // w >= 0
        pairs[pos] = (wb << 17) | (uint32_t)(q.x >> 8);
    }
}

// ---------------- weight hi/lo split (+ bucket cursor init) ----------------

__global__ __launch_bounds__(256) void k_wsplit(const float* __restrict__ Wrel_mid,
                                                const float* __restrict__ Wroot_mid,
                                                uint16_t* __restrict__ WgH,
                                                uint16_t* __restrict__ WgL,
                                                uint16_t* __restrict__ WrH,
                                                uint16_t* __restrict__ WrL,
                                                int* __restrict__ bcur) {
    int i = blockIdx.x * blockDim.x + threadIdx.x;
    if (i < NBKT) bcur[i] = i * CAP;
    if (i >= 3 * 4096) return;
    float a = Wrel_mid[i];
    uint32_t ah = rne_bf16(a);
    float al = a - __uint_as_float(ah << 16);
    WgH[i] = (uint16_t)ah;
    WgL[i] = (uint16_t)rne_bf16(al);
    float b = Wroot_mid[i];
    uint32_t bh = rne_bf16(b);
    float bl = b - __uint_as_float(bh << 16);
    WrH[i] = (uint16_t)bh;
    WrL[i] = (uint16_t)rne_bf16(bl);
}

// ---------------- shared epilogue: 16-node h (LDS) -> G,R via LDS tiles ----

__device__ __forceinline__ void mfma_epilogue(
        int lane, int w, const uint32_t* sH,
        const uint16_t* __restrict__ WgH, const uint16_t* __restrict__ WgL,
        const uint16_t* __restrict__ WrH, const uint16_t* __restrict__ WrL,
        const float* __restrict__ brel,
        uint16_t* sG, uint16_t* sR) {
    int row = lane & 15;
    int quad = lane >> 4;
    int kb = quad * 8;
    bf16x8 ah0 = *(const bf16x8*)&sH[row * 36 + quad * 4];
    bf16x8 ah1 = *(const bf16x8*)&sH[row * 36 + 16 + quad * 4];
    int oc = w * 16 + row;
    {
        bf16x8 bh0 = *(const bf16x8*)&WgH[oc * 64 + kb];
        bf16x8 bh1 = *(const bf16x8*)&WgH[oc * 64 + 32 + kb];
        bf16x8 bl0 = *(const bf16x8*)&WgL[oc * 64 + kb];
        bf16x8 bl1 = *(const bf16x8*)&WgL[oc * 64 + 32 + kb];
        f32x4 acc = {0.f, 0.f, 0.f, 0.f};
        acc = __builtin_amdgcn_mfma_f32_16x16x32_bf16(ah0, bh0, acc, 0, 0, 0);
        acc = __builtin_amdgcn_mfma_f32_16x16x32_bf16(ah1, bh1, acc, 0, 0, 0);
        acc = __builtin_amdgcn_mfma_f32_16x16x32_bf16(ah0, bl0, acc, 0, 0, 0);
        acc = __builtin_amdgcn_mfma_f32_16x16x32_bf16(ah1, bl1, acc, 0, 0, 0);
        #pragma unroll
        for (int r = 0; r < 4; r++)
            sG[(quad * 4 + r) * 68 + oc] = (uint16_t)rne_bf16(acc[r]);
    }
    {
        bf16x8 bh0 = *(const bf16x8*)&WrH[oc * 64 + kb];
        bf16x8 bh1 = *(const bf16x8*)&WrH[oc * 64 + 32 + kb];
        bf16x8 bl0 = *(const bf16x8*)&WrL[oc * 64 + kb];
        bf16x8 bl1 = *(const bf16x8*)&WrL[oc * 64 + 32 + kb];
        float bias = brel[oc];
        f32x4 acc = {bias, bias, bias, bias};
        acc = __builtin_amdgcn_mfma_f32_16x16x32_bf16(ah0, bh0, acc, 0, 0, 0);
        acc = __builtin_amdgcn_mfma_f32_16x16x32_bf16(ah1, bh1, acc, 0, 0, 0);
        acc = __builtin_amdgcn_mfma_f32_16x16x32_bf16(ah0, bl0, acc, 0, 0, 0);
        acc = __builtin_amdgcn_mfma_f32_16x16x32_bf16(ah1, bl1, acc, 0, 0, 0);
        #pragma unroll
        for (int r = 0; r < 4; r++)
            sR[(quad * 4 + r) * 68 + oc] = (uint16_t)rne_bf16(acc[r]);
    }
}

__device__ __forceinline__ void epilogue_writeout(
        int tid, int blk16, const uint16_t* sG, const uint16_t* sR,
        uint16_t* __restrict__ Gout, uint16_t* __restrict__ Rout) {
    const uint32_t* sGd = (const uint32_t*)sG;   // stride 34 dwords/node
    const uint32_t* sRd = (const uint32_t*)sR;
    uint32_t* Gd = (uint32_t*)Gout;
    uint32_t* Rd = (uint32_t*)Rout;
    #pragma unroll
    for (int it = 0; it < 2; it++) {
        int idx = it * 256 + tid;
        int nd = idx >> 5, col = idx & 31;
        Gd[(blk16 + nd) * 32 + col] = sGd[nd * 34 + col];
        Rd[(blk16 + nd) * 32 + col] = sRd[nd * 34 + col];
    }
}

// ---------------- layers ----------------

// layer 0 (fused): edge-parallel aggregation (all waves, shfl reduce), then
// h0 = relu(...) staged in LDS, MFMA epilogue -> G1,R1.
__global__ __launch_bounds__(256) void k_l0pre(
        const int* __restrict__ offs, const int* __restrict__ ends,
        const uint32_t* __restrict__ pairs, const float* __restrict__ x,
        const float* __restrict__ Wrel0, const float* __restrict__ brel0,
        const float* __restrict__ Wroot0,
        const uint16_t* __restrict__ WgH, const uint16_t* __restrict__ WgL,
        const uint16_t* __restrict__ WrH, const uint16_t* __restrict__ WrL,
        const float* __restrict__ brel,
        uint16_t* __restrict__ Gout, uint16_t* __restrict__ Rout) {
    __shared__ uint32_t sH[16 * 36];
    __shared__ uint16_t sG[16 * 68];
    __shared__ uint16_t sR[16 * 68];
    int c = threadIdx.x & 63;
    int w = threadIdx.x >> 6;
    int blk16 = blockIdx.x * 16;
    float agg[4];
    #pragma unroll
    for (int t = 0; t < 4; t++) {
        int node = blk16 + w * 4 + t;
        int b = offs[node], e = ends[node];
        float pp = 0.f;
        for (int j = b + c; j < e; j += 64) {
            uint32_t r = pairs[j];
            pp += __uint_as_float((r >> 17) << 16) * x[r & 0x1ffffu];
        }
        for (int o = 32; o > 0; o >>= 1) pp += __shfl_down(pp, o, 64);
        agg[t] = __shfl(pp, 0, 64);
    }
    float wr = Wrel0[c], br = brel0[c], wo = Wroot0[c];
    #pragma unroll
    for (int t = 0; t < 4; t++) {
        int node = blk16 + w * 4 + t;
        float v = agg[t] * wr + br + x[node] * wo;
        v = v > 0.f ? v : 0.f;
        uint32_t hb = rne_bf16(v);
        uint32_t pn = (uint32_t)__shfl_xor((int)hb, 1, 64);
        if (!(c & 1)) sH[(w * 4 + t) * 36 + (c >> 1)] = hb | (pn << 16);
    }
    __syncthreads();
    mfma_epilogue(c, w, sH, WgH, WgL, WrH, WrL, brel, sG, sR);
    __syncthreads();
    epilogue_writeout((int)threadIdx.x, blk16, sG, sR, Gout, Rout);
}

// Fused aggregation + pre-transform (round-14 validated: 16-deep load
// batches, 4 FMA chains/node, launch_bounds(256,4), Rb prefetch).
template <bool LAST>
__global__ __launch_bounds__(256, 4) void k_aggfused(
        const int* __restrict__ offs, const int* __restrict__ ends,
        const uint32_t* __restrict__ pairs,
        const uint16_t* __restrict__ Gb, const uint16_t* __restrict__ Rb,
        const uint16_t* __restrict__ WgH, const uint16_t* __restrict__ WgL,
        const uint16_t* __restrict__ WrH, const uint16_t* __restrict__ WrL,
        const float* __restrict__ brel,
        uint16_t* __restrict__ Gout, uint16_t* __restrict__ Rout,
        const float* __restrict__ WrelL, const float* __restrict__ WrootL,
        float* __restrict__ sarr, float* __restrict__ rarr) {
    __shared__ uint32_t sH[16 * 36];
    __shared__ uint16_t sG[16 * 68];
    __shared__ uint16_t sR[16 * 68];
    int c = threadIdx.x & 63;
    int w = threadIdx.x >> 6;
    int blk16 = blockIdx.x * 16;
    int n0 = blk16 + w * 4;
    int ov = 0;
    if (c < 4) ov = offs[n0 + c];
    else if (c == 4) ov = ends[n0 + 3];
    int bnd[5];
    bnd[0] = __builtin_amdgcn_readlane(ov, 0);
    bnd[1] = __builtin_amdgcn_readlane(ov, 1);
    bnd[2] = __builtin_amdgcn_readlane(ov, 2);
    bnd[3] = __builtin_amdgcn_readlane(ov, 3);
    bnd[4] = __builtin_amdgcn_readlane(ov, 4);

    // prefetch R rows (consumed only in the epilogue)
    uint32_t ur[4];
    #pragma unroll
    for (int t = 0; t < 4; t++) ur[t] = Rb[(n0 + t) * 64 + c];

    float acc[4][4];
    #pragma unroll
    for (int t = 0; t < 4; t++)
        #pragma unroll
        for (int q = 0; q < 4; q++) acc[t][q] = 0.f;

    for (int cb = bnd[0]; cb < bnd[4]; cb += 64) {
        int n = bnd[4] - cb; if (n > 64) n = 64;
        uint32_t p = (c < n) ? pairs[cb + c] : 0u;
        #pragma unroll
        for (int t = 0; t < 4; t++) {
            int lo = bnd[t]     > cb     ? bnd[t]     : cb;
            int hi = bnd[t + 1] < cb + n ? bnd[t + 1] : cb + n;
            int j = lo;
            for (; j + 16 <= hi; j += 16) {
                int jj = j - cb;
                uint32_t rr[16], uu[16];
                #pragma unroll
                for (int q = 0; q < 16; q++)
                    rr[q] = __builtin_amdgcn_readlane(p, jj + q);
                #pragma unroll
                for (int q = 0; q < 16; q++)
                    uu[q] = Gb[(rr[q] & 0x1ffffu) * 64 + c];
                #pragma unroll
                for (int q = 0; q < 16; q++)
                    acc[t][q & 3] += __uint_as_float((rr[q] >> 17) << 16)
                                   * __uint_as_float(uu[q] << 16);
            }
            for (; j + 8 <= hi; j += 8) {
                int jj = j - cb;
                uint32_t rr[8], uu[8];
                #pragma unroll
                for (int q = 0; q < 8; q++)
                    rr[q] = __builtin_amdgcn_readlane(p, jj + q);
                #pragma unroll
                for (int q = 0; q < 8; q++)
                    uu[q] = Gb[(rr[q] & 0x1ffffu) * 64 + c];
                #pragma unroll
                for (int q = 0; q < 8; q++)
                    acc[t][q & 3] += __uint_as_float((rr[q] >> 17) << 16)
                                   * __uint_as_float(uu[q] << 16);
            }
            for (; j + 4 <= hi; j += 4) {
                int jj = j - cb;
                uint32_t rr[4], uu[4];
                #pragma unroll
                for (int q = 0; q < 4; q++)
                    rr[q] = __builtin_amdgcn_readlane(p, jj + q);
                #pragma unroll
                for (int q = 0; q < 4; q++)
                    uu[q] = Gb[(rr[q] & 0x1ffffu) * 64 + c];
                #pragma unroll
                for (int q = 0; q < 4; q++)
                    acc[t][q] += __uint_as_float((rr[q] >> 17) << 16)
                               * __uint_as_float(uu[q] << 16);
            }
            for (; j < hi; j++) {
                int jj = j - cb;
                uint32_t r = __builtin_amdgcn_readlane(p, jj);
                uint32_t u = Gb[(r & 0x1ffffu) * 64 + c];
                acc[t][0] += __uint_as_float((r >> 17) << 16)
                           * __uint_as_float(u << 16);
            }
        }
    }
    #pragma unroll
    for (int t = 0; t < 4; t++) {
        float v = (acc[t][0] + acc[t][1]) + (acc[t][2] + acc[t][3])
                + __uint_as_float(ur[t] << 16);
        v = v > 0.f ? v : 0.f;
        if (!LAST) {
            uint32_t hb = rne_bf16(v);
            uint32_t pn = (uint32_t)__shfl_xor((int)hb, 1, 64);
            if (!(c & 1)) sH[(w * 4 + t) * 36 + (c >> 1)] = hb | (pn << 16);
        } else {
            float a = v * WrelL[c];
            float r = v * WrootL[c];
            for (int o = 32; o > 0; o >>= 1) {
                a += __shfl_down(a, o, 64);
                r += __shfl_down(r, o, 64);
            }
            if (c == 0) { sarr[n0 + t] = a; rarr[n0 + t] = r; }
        }
    }
    if (!LAST) {
        __syncthreads();
        mfma_epilogue(c, w, sH, WgH, WgL, WrH, WrL, brel, sG, sR);
        __syncthreads();
        epilogue_writeout((int)threadIdx.x, blk16, sG, sR, Gout, Rout);
    }
}

__global__ void k_last(const int* __restrict__ offs, const int* __restrict__ ends,
                       const uint32_t* __restrict__ pairs,
                       const float* __restrict__ sarr, const float* __restrict__ rarr,
                       const float* __restrict__ brelL, float* __restrict__ out) {
    int i = blockIdx.x * blockDim.x + threadIdx.x;
    if (i >= NN) return;
    float a0 = rarr[i] + brelL[0], a1 = 0.f;
    int b = offs[i], e = ends[i];
    int j = b;
    for (; j + 2 <= e; j += 2) {
        uint32_t r0 = pairs[j], r1 = pairs[j + 1];
        a0 += __uint_as_float((r0 >> 17) << 16) * sarr[r0 & 0x1ffffu];
        a1 += __uint_as_float((r1 >> 17) << 16) * sarr[r1 & 0x1ffffu];
    }
    for (; j < e; j++) {
        uint32_t r = pairs[j];
        a0 += __uint_as_float((r >> 17) << 16) * sarr[r & 0x1ffffu];
    }
    out[i] = a0 + a1;
}

extern "C" void kernel_launch(void* const* d_in, const int* in_sizes, int n_in,
                              void* d_out, int out_size, void* d_ws, size_t ws_size,
                              hipStream_t stream) {
    const float* x        = (const float*)d_in[0];
    const int*   ei       = (const int*)d_in[1];
    const float* ew       = (const float*)d_in[2];
    const float* Wrel0    = (const float*)d_in[3];
    const float* brel0    = (const float*)d_in[4];
    const float* Wroot0   = (const float*)d_in[5];
    const float* Wrel_mid = (const float*)d_in[6];
    const float* brel_mid = (const float*)d_in[7];
    const float* Wroot_mid= (const float*)d_in[8];
    const float* WrelL    = (const float*)d_in[9];
    const float* brelL    = (const float*)d_in[10];
    const float* WrootL   = (const float*)d_in[11];
    float* out = (float*)d_out;

    const int* src  = ei;
    const int* dstp = ei + NE;

    char* w = (char*)d_ws;
    size_t o = 0;
    auto alloc = [&](size_t b) -> void* {
        void* r = (void*)(w + o);
        o += (b + 255) & ~(size_t)255;
        return r;
    };
    int*      offs  = (int*)alloc((size_t)NN * 4);
    int*      ends  = (int*)alloc((size_t)NN * 4);
    int*      bcur  = (int*)alloc((size_t)NBKT * 4);
    uint16_t* WgH   = (uint16_t*)alloc((size_t)3 * 4096 * 2);
    uint16_t* WgL   = (uint16_t*)alloc((size_t)3 * 4096 * 2);
    uint16_t* WrH   = (uint16_t*)alloc((size_t)3 * 4096 * 2);
    uint16_t* WrL   = (uint16_t*)alloc((size_t)3 * 4096 * 2);
    float*    sarr  = (float*)alloc((size_t)NN * 4);
    float*    rarr  = (float*)alloc((size_t)NN * 4);
    uint32_t* pairs = (uint32_t*)alloc((size_t)NBKT * CAP * 4);  // 12.8 MB padded
    uint16_t* GbA   = (uint16_t*)alloc((size_t)NN * HID * 2);    // 12.8 MB
    uint16_t* RbA   = (uint16_t*)alloc((size_t)NN * HID * 2);
    uint16_t* GbB   = (uint16_t*)alloc((size_t)NN * HID * 2);    // GbB/RbB contiguous
    uint16_t* RbB   = (uint16_t*)alloc((size_t)NN * HID * 2);
    (void)RbB;
    // bpairs (NBKT*CAP*8B = 25.6MB) aliases GbB+RbB (contiguous; dead before
    // mid layer 1 writes set B)
    int2*  bpairs = (int2*)GbB;

    // weight split + bucket cursor init (one launch)
    k_wsplit<<<(3 * 4096 + 255) / 256, 256, 0, stream>>>(
        Wrel_mid, Wroot_mid, WgH, WgL, WrH, WrL, bcur);

    // CSR build (padded buckets)
    k_bpart<<<NTILE, 256, 0, stream>>>(src, dstp, ew, bcur, bpairs);
    k_bcsr<<<NBKT, 256, 0, stream>>>(bcur, bpairs, offs, ends, pairs);

    // layer 0 (agg + transform + pre) -> G1,R1 (set A)
    k_l0pre<<<NN / 16, 256, 0, stream>>>(
        offs, ends, pairs, x, Wrel0, brel0, Wroot0,
        WgH, WgL, WrH, WrL, brel_mid, GbA, RbA);

    // mid layer 1: consume set A, produce set B (weights index 1)
    k_aggfused<false><<<NN / 16, 256, 0, stream>>>(
        offs, ends, pairs, GbA, RbA,
        WgH + 4096, WgL + 4096, WrH + 4096, WrL + 4096, brel_mid + HID,
        GbB, RbB, WrelL, WrootL, sarr, rarr);
    // mid layer 2: consume set B, produce set A (weights index 2)
    k_aggfused<false><<<NN / 16, 256, 0, stream>>>(
        offs, ends, pairs, GbB, RbB,
        WgH + 2 * 4096, WgL + 2 * 4096, WrH + 2 * 4096, WrL + 2 * 4096,
        brel_mid + 2 * HID, GbA, RbA, WrelL, WrootL, sarr, rarr);
    // mid layer 3 (LAST): consume set A, produce s/r scalars
    k_aggfused<true><<<NN / 16, 256, 0, stream>>>(
        offs, ends, pairs, GbA, RbA,
        WgH, WgL, WrH, WrL, brel_mid,
        GbB, RbB, WrelL, WrootL, sarr, rarr);

    // final edge pass on scalars
    k_last<<<(NN + 255) / 256, 256, 0, stream>>>(offs, ends, pairs, sarr, rarr, brelL, out);
}

// Round 18
// 327.627 us; speedup vs baseline: 1.2920x; 1.0047x over previous
//
#include <hip/hip_runtime.h>
#include <stdint.h>

// GraphConv x5 on MI355X — round 18.
// vs round 17 (329us validated): k_bcsr stages the bucket's edges in LDS
// (CAP*8B = 64KB) — the histogram and scatter passes previously each read
// the 12.8MB bpairs array from global (2x); now one global read + LDS
// re-reads. Everything else unchanged.

#define NN 100000
#define NE 1600000
#define HID 64
#define NBKT 391            // ceil(NN/256), bucket = dst >> 8
#define CAP 8192            // padded bucket capacity (mean 4092, +64 sigma)
#define TILE 4096
#define EPT 16              // TILE / 256
#define NTILE ((NE + TILE - 1) / TILE)   // 391

typedef __attribute__((ext_vector_type(8))) short bf16x8;
typedef __attribute__((ext_vector_type(4))) float f32x4;

__device__ __forceinline__ uint32_t rne_bf16(float v) {
    uint32_t u = __float_as_uint(v);
    return (u + 0x7fffu + ((u >> 16) & 1u)) >> 16;
}

// ---------------- CSR build ----------------

__global__ __launch_bounds__(256) void k_bpart(const int* __restrict__ src,
                                               const int* __restrict__ dst,
                                               const float* __restrict__ w,
                                               int* __restrict__ bcur,
                                               int2* __restrict__ bpairs) {
    __shared__ int hcnt[NBKT];
    __shared__ int hbase[NBKT];
    int tile0 = blockIdx.x * TILE;
    for (int t = threadIdx.x; t < NBKT; t += 256) hcnt[t] = 0;
    __syncthreads();

    int   pk[EPT];
    int   bk[EPT];
    float wv[EPT];
    #pragma unroll
    for (int k = 0; k < EPT; k++) {
        int e = tile0 + threadIdx.x + k * 256;
        if (e < NE) {
            int d = dst[e];
            int b = d >> 8;
            pk[k] = (src[e] << 8) | (d & 255);
            wv[k] = w[e];
            bk[k] = b;
            atomicAdd(&hcnt[b], 1);
        } else {
            bk[k] = -1;
        }
    }
    __syncthreads();
    for (int t = threadIdx.x; t < NBKT; t += 256) {
        int c = hcnt[t];
        hbase[t] = c ? atomicAdd(&bcur[t], c) : 0;
        hcnt[t] = 0;
    }
    __syncthreads();
    #pragma unroll
    for (int k = 0; k < EPT; k++) {
        if (bk[k] >= 0) {
            int pos = hbase[bk[k]] + atomicAdd(&hcnt[bk[k]], 1);
            bpairs[pos] = make_int2(pk[k], __float_as_int(wv[k]));
        }
    }
}

// one block per bucket: stage bucket in LDS, then LDS counting sort.
__global__ __launch_bounds__(256) void k_bcsr(const int* __restrict__ bcur,
                                              const int2* __restrict__ bpairs,
                                              int* __restrict__ offs,
                                              int* __restrict__ ends,
                                              uint32_t* __restrict__ pairs) {
    __shared__ int2 sE[CAP];        // 64 KB bucket stage
    __shared__ int cnt[256];
    __shared__ int scn[256];
    __shared__ int cur[256];
    int k = blockIdx.x, t = threadIdx.x;
    int base = k * CAP;
    int scnt = bcur[k] - base;
    cnt[t] = 0;
    __syncthreads();
    for (int j = t; j < scnt; j += 256) {
        int2 q = bpairs[base + j];
        sE[j] = q;
        atomicAdd(&cnt[q.x & 255], 1);
    }
    __syncthreads();
    int v = cnt[t], acc = v;
    scn[t] = v;
    __syncthreads();
    for (int off = 1; off < 256; off <<= 1) {
        int u = (t >= off) ? scn[t - off] : 0;
        __syncthreads();
        acc += u;
        scn[t] = acc;
        __syncthreads();
    }
    int excl = acc - v;
    cur[t] = excl;
    int d = (k << 8) + t;
    if (d < NN) {
        offs[d] = base + excl;
        ends[d] = base + excl + v;
    }
    __syncthreads();
    for (int j = t; j < scnt; j += 256) {
        int2 q = sE[j];
        int pos = base + atomicAdd(&cur[q.x & 255], 1);
        uint32_t wb = rne_bf16(__int_as_float(q.y)) & 0x7fffu;   // w >= 0
        pairs[pos] = (wb << 17) | (uint32_t)(q.x >> 8);
    }
}

// ---------------- weight hi/lo split (+ bucket cursor init) ----------------

__global__ __launch_bounds__(256) void k_wsplit(const float* __restrict__ Wrel_mid,
                                                const float* __restrict__ Wroot_mid,
                                                uint16_t* __restrict__ WgH,
                                                uint16_t* __restrict__ WgL,
                                                uint16_t* __restrict__ WrH,
                                                uint16_t* __restrict__ WrL,
                                                int* __restrict__ bcur) {
    int i = blockIdx.x * blockDim.x + threadIdx.x;
    if (i < NBKT) bcur[i] = i * CAP;
    if (i >= 3 * 4096) return;
    float a = Wrel_mid[i];
    uint32_t ah = rne_bf16(a);
    float al = a - __uint_as_float(ah << 16);
    WgH[i] = (uint16_t)ah;
    WgL[i] = (uint16_t)rne_bf16(al);
    float b = Wroot_mid[i];
    uint32_t bh = rne_bf16(b);
    float bl = b - __uint_as_float(bh << 16);
    WrH[i] = (uint16_t)bh;
    WrL[i] = (uint16_t)rne_bf16(bl);
}

// ---------------- shared epilogue: 16-node h (LDS) -> G,R via LDS tiles ----

__device__ __forceinline__ void mfma_epilogue(
        int lane, int w, const uint32_t* sH,
        const uint16_t* __restrict__ WgH, const uint16_t* __restrict__ WgL,
        const uint16_t* __restrict__ WrH, const uint16_t* __restrict__ WrL,
        const float* __restrict__ brel,
        uint16_t* sG, uint16_t* sR) {
    int row = lane & 15;
    int quad = lane >> 4;
    int kb = quad * 8;
    bf16x8 ah0 = *(const bf16x8*)&sH[row * 36 + quad * 4];
    bf16x8 ah1 = *(const bf16x8*)&sH[row * 36 + 16 + quad * 4];
    int oc = w * 16 + row;
    {
        bf16x8 bh0 = *(const bf16x8*)&WgH[oc * 64 + kb];
        bf16x8 bh1 = *(const bf16x8*)&WgH[oc * 64 + 32 + kb];
        bf16x8 bl0 = *(const bf16x8*)&WgL[oc * 64 + kb];
        bf16x8 bl1 = *(const bf16x8*)&WgL[oc * 64 + 32 + kb];
        f32x4 acc = {0.f, 0.f, 0.f, 0.f};
        acc = __builtin_amdgcn_mfma_f32_16x16x32_bf16(ah0, bh0, acc, 0, 0, 0);
        acc = __builtin_amdgcn_mfma_f32_16x16x32_bf16(ah1, bh1, acc, 0, 0, 0);
        acc = __builtin_amdgcn_mfma_f32_16x16x32_bf16(ah0, bl0, acc, 0, 0, 0);
        acc = __builtin_amdgcn_mfma_f32_16x16x32_bf16(ah1, bl1, acc, 0, 0, 0);
        #pragma unroll
        for (int r = 0; r < 4; r++)
            sG[(quad * 4 + r) * 68 + oc] = (uint16_t)rne_bf16(acc[r]);
    }
    {
        bf16x8 bh0 = *(const bf16x8*)&WrH[oc * 64 + kb];
        bf16x8 bh1 = *(const bf16x8*)&WrH[oc * 64 + 32 + kb];
        bf16x8 bl0 = *(const bf16x8*)&WrL[oc * 64 + kb];
        bf16x8 bl1 = *(const bf16x8*)&WrL[oc * 64 + 32 + kb];
        float bias = brel[oc];
        f32x4 acc = {bias, bias, bias, bias};
        acc = __builtin_amdgcn_mfma_f32_16x16x32_bf16(ah0, bh0, acc, 0, 0, 0);
        acc = __builtin_amdgcn_mfma_f32_16x16x32_bf16(ah1, bh1, acc, 0, 0, 0);
        acc = __builtin_amdgcn_mfma_f32_16x16x32_bf16(ah0, bl0, acc, 0, 0, 0);
        acc = __builtin_amdgcn_mfma_f32_16x16x32_bf16(ah1, bl1, acc, 0, 0, 0);
        #pragma unroll
        for (int r = 0; r < 4; r++)
            sR[(quad * 4 + r) * 68 + oc] = (uint16_t)rne_bf16(acc[r]);
    }
}

__device__ __forceinline__ void epilogue_writeout(
        int tid, int blk16, const uint16_t* sG, const uint16_t* sR,
        uint16_t* __restrict__ Gout, uint16_t* __restrict__ Rout) {
    const uint32_t* sGd = (const uint32_t*)sG;   // stride 34 dwords/node
    const uint32_t* sRd = (const uint32_t*)sR;
    uint32_t* Gd = (uint32_t*)Gout;
    uint32_t* Rd = (uint32_t*)Rout;
    #pragma unroll
    for (int it = 0; it < 2; it++) {
        int idx = it * 256 + tid;
        int nd = idx >> 5, col = idx & 31;
        Gd[(blk16 + nd) * 32 + col] = sGd[nd * 34 + col];
        Rd[(blk16 + nd) * 32 + col] = sRd[nd * 34 + col];
    }
}

// ---------------- layers ----------------

// layer 0 (fused): edge-parallel aggregation (all waves, shfl reduce), then
// h0 = relu(...) staged in LDS, MFMA epilogue -> G1,R1.
__global__ __launch_bounds__(256) void k_l0pre(
        const int* __restrict__ offs, const int* __restrict__ ends,
        const uint32_t* __restrict__ pairs, const float* __restrict__ x,
        const float* __restrict__ Wrel0, const float* __restrict__ brel0,
        const float* __restrict__ Wroot0,
        const uint16_t* __restrict__ WgH, const uint16_t* __restrict__ WgL,
        const uint16_t* __restrict__ WrH, const uint16_t* __restrict__ WrL,
        const float* __restrict__ brel,
        uint16_t* __restrict__ Gout, uint16_t* __restrict__ Rout) {
    __shared__ uint32_t sH[16 * 36];
    __shared__ uint16_t sG[16 * 68];
    __shared__ uint16_t sR[16 * 68];
    int c = threadIdx.x & 63;
    int w = threadIdx.x >> 6;
    int blk16 = blockIdx.x * 16;
    float agg[4];
    #pragma unroll
    for (int t = 0; t < 4; t++) {
        int node = blk16 + w * 4 + t;
        int b = offs[node], e = ends[node];
        float pp = 0.f;
        for (int j = b + c; j < e; j += 64) {
            uint32_t r = pairs[j];
            pp += __uint_as_float((r >> 17) << 16) * x[r & 0x1ffffu];
        }
        for (int o = 32; o > 0; o >>= 1) pp += __shfl_down(pp, o, 64);
        agg[t] = __shfl(pp, 0, 64);
    }
    float wr = Wrel0[c], br = brel0[c], wo = Wroot0[c];
    #pragma unroll
    for (int t = 0; t < 4; t++) {
        int node = blk16 + w * 4 + t;
        float v = agg[t] * wr + br + x[node] * wo;
        v = v > 0.f ? v : 0.f;
        uint32_t hb = rne_bf16(v);
        uint32_t pn = (uint32_t)__shfl_xor((int)hb, 1, 64);
        if (!(c & 1)) sH[(w * 4 + t) * 36 + (c >> 1)] = hb | (pn << 16);
    }
    __syncthreads();
    mfma_epilogue(c, w, sH, WgH, WgL, WrH, WrL, brel, sG, sR);
    __syncthreads();
    epilogue_writeout((int)threadIdx.x, blk16, sG, sR, Gout, Rout);
}

// Fused aggregation + pre-transform (round-14 validated: 16-deep load
// batches, 4 FMA chains/node, launch_bounds(256,4), Rb prefetch).
template <bool LAST>
__global__ __launch_bounds__(256, 4) void k_aggfused(
        const int* __restrict__ offs, const int* __restrict__ ends,
        const uint32_t* __restrict__ pairs,
        const uint16_t* __restrict__ Gb, const uint16_t* __restrict__ Rb,
        const uint16_t* __restrict__ WgH, const uint16_t* __restrict__ WgL,
        const uint16_t* __restrict__ WrH, const uint16_t* __restrict__ WrL,
        const float* __restrict__ brel,
        uint16_t* __restrict__ Gout, uint16_t* __restrict__ Rout,
        const float* __restrict__ WrelL, const float* __restrict__ WrootL,
        float* __restrict__ sarr, float* __restrict__ rarr) {
    __shared__ uint32_t sH[16 * 36];
    __shared__ uint16_t sG[16 * 68];
    __shared__ uint16_t sR[16 * 68];
    int c = threadIdx.x & 63;
    int w = threadIdx.x >> 6;
    int blk16 = blockIdx.x * 16;
    int n0 = blk16 + w * 4;
    int ov = 0;
    if (c < 4) ov = offs[n0 + c];
    else if (c == 4) ov = ends[n0 + 3];
    int bnd[5];
    bnd[0] = __builtin_amdgcn_readlane(ov, 0);
    bnd[1] = __builtin_amdgcn_readlane(ov, 1);
    bnd[2] = __builtin_amdgcn_readlane(ov, 2);
    bnd[3] = __builtin_amdgcn_readlane(ov, 3);
    bnd[4] = __builtin_amdgcn_readlane(ov, 4);

    // prefetch R rows (consumed only in the epilogue)
    uint32_t ur[4];
    #pragma unroll
    for (int t = 0; t < 4; t++) ur[t] = Rb[(n0 + t) * 64 + c];

    float acc[4][4];
    #pragma unroll
    for (int t = 0; t < 4; t++)
        #pragma unroll
        for (int q = 0; q < 4; q++) acc[t][q] = 0.f;

    for (int cb = bnd[0]; cb < bnd[4]; cb += 64) {
        int n = bnd[4] - cb; if (n > 64) n = 64;
        uint32_t p = (c < n) ? pairs[cb + c] : 0u;
        #pragma unroll
        for (int t = 0; t < 4; t++) {
            int lo = bnd[t]     > cb     ? bnd[t]     : cb;
            int hi = bnd[t + 1] < cb + n ? bnd[t + 1] : cb + n;
            int j = lo;
            for (; j + 16 <= hi; j += 16) {
                int jj = j - cb;
                uint32_t rr[16], uu[16];
                #pragma unroll
                for (int q = 0; q < 16; q++)
                    rr[q] = __builtin_amdgcn_readlane(p, jj + q);
                #pragma unroll
                for (int q = 0; q < 16; q++)
                    uu[q] = Gb[(rr[q] & 0x1ffffu) * 64 + c];
                #pragma unroll
                for (int q = 0; q < 16; q++)
                    acc[t][q & 3] += __uint_as_float((rr[q] >> 17) << 16)
                                   * __uint_as_float(uu[q] << 16);
            }
            for (; j + 8 <= hi; j += 8) {
                int jj = j - cb;
                uint32_t rr[8], uu[8];
                #pragma unroll
                for (int q = 0; q < 8; q++)
                    rr[q] = __builtin_amdgcn_readlane(p, jj + q);
                #pragma unroll
                for (int q = 0; q < 8; q++)
                    uu[q] = Gb[(rr[q] & 0x1ffffu) * 64 + c];
                #pragma unroll
                for (int q = 0; q < 8; q++)
                    acc[t][q & 3] += __uint_as_float((rr[q] >> 17) << 16)
                                   * __uint_as_float(uu[q] << 16);
            }
            for (; j + 4 <= hi; j += 4) {
                int jj = j - cb;
                uint32_t rr[4], uu[4];
                #pragma unroll
                for (int q = 0; q < 4; q++)
                    rr[q] = __builtin_amdgcn_readlane(p, jj + q);
                #pragma unroll
                for (int q = 0; q < 4; q++)
                    uu[q] = Gb[(rr[q] & 0x1ffffu) * 64 + c];
                #pragma unroll
                for (int q = 0; q < 4; q++)
                    acc[t][q] += __uint_as_float((rr[q] >> 17) << 16)
                               * __uint_as_float(uu[q] << 16);
            }
            for (; j < hi; j++) {
                int jj = j - cb;
                uint32_t r = __builtin_amdgcn_readlane(p, jj);
                uint32_t u = Gb[(r & 0x1ffffu) * 64 + c];
                acc[t][0] += __uint_as_float((r >> 17) << 16)
                           * __uint_as_float(u << 16);
            }
        }
    }
    #pragma unroll
    for (int t = 0; t < 4; t++) {
        float v = (acc[t][0] + acc[t][1]) + (acc[t][2] + acc[t][3])
                + __uint_as_float(ur[t] << 16);
        v = v > 0.f ? v : 0.f;
        if (!LAST) {
            uint32_t hb = rne_bf16(v);
            uint32_t pn = (uint32_t)__shfl_xor((int)hb, 1, 64);
            if (!(c & 1)) sH[(w * 4 + t) * 36 + (c >> 1)] = hb | (pn << 16);
        } else {
            float a = v * WrelL[c];
            float r = v * WrootL[c];
            for (int o = 32; o > 0; o >>= 1) {
                a += __shfl_down(a, o, 64);
                r += __shfl_down(r, o, 64);
            }
            if (c == 0) { sarr[n0 + t] = a; rarr[n0 + t] = r; }
        }
    }
    if (!LAST) {
        __syncthreads();
        mfma_epilogue(c, w, sH, WgH, WgL, WrH, WrL, brel, sG, sR);
        __syncthreads();
        epilogue_writeout((int)threadIdx.x, blk16, sG, sR, Gout, Rout);
    }
}

__global__ void k_last(const int* __restrict__ offs, const int* __restrict__ ends,
                       const uint32_t* __restrict__ pairs,
                       const float* __restrict__ sarr, const float* __restrict__ rarr,
                       const float* __restrict__ brelL, float* __restrict__ out) {
    int i = blockIdx.x * blockDim.x + threadIdx.x;
    if (i >= NN) return;
    float a0 = rarr[i] + brelL[0], a1 = 0.f;
    int b = offs[i], e = ends[i];
    int j = b;
    for (; j + 2 <= e; j += 2) {
        uint32_t r0 = pairs[j], r1 = pairs[j + 1];
        a0 += __uint_as_float((r0 >> 17) << 16) * sarr[r0 & 0x1ffffu];
        a1 += __uint_as_float((r1 >> 17) << 16) * sarr[r1 & 0x1ffffu];
    }
    for (; j < e; j++) {
        uint32_t r = pairs[j];
        a0 += __uint_as_float((r >> 17) << 16) * sarr[r & 0x1ffffu];
    }
    out[i] = a0 + a1;
}

extern "C" void kernel_launch(void* const* d_in, const int* in_sizes, int n_in,
                              void* d_out, int out_size, void* d_ws, size_t ws_size,
                              hipStream_t stream) {
    const float* x        = (const float*)d_in[0];
    const int*   ei       = (const int*)d_in[1];
    const float* ew       = (const float*)d_in[2];
    const float* Wrel0    = (const float*)d_in[3];
    const float* brel0    = (const float*)d_in[4];
    const float* Wroot0   = (const float*)d_in[5];
    const float* Wrel_mid = (const float*)d_in[6];
    const float* brel_mid = (const float*)d_in[7];
    const float* Wroot_mid= (const float*)d_in[8];
    const float* WrelL    = (const float*)d_in[9];
    const float* brelL    = (const float*)d_in[10];
    const float* WrootL   = (const float*)d_in[11];
    float* out = (float*)d_out;

    const int* src  = ei;
    const int* dstp = ei + NE;

    char* w = (char*)d_ws;
    size_t o = 0;
    auto alloc = [&](size_t b) -> void* {
        void* r = (void*)(w + o);
        o += (b + 255) & ~(size_t)255;
        return r;
    };
    int*      offs  = (int*)alloc((size_t)NN * 4);
    int*      ends  = (int*)alloc((size_t)NN * 4);
    int*      bcur  = (int*)alloc((size_t)NBKT * 4);
    uint16_t* WgH   = (uint16_t*)alloc((size_t)3 * 4096 * 2);
    uint16_t* WgL   = (uint16_t*)alloc((size_t)3 * 4096 * 2);
    uint16_t* WrH   = (uint16_t*)alloc((size_t)3 * 4096 * 2);
    uint16_t* WrL   = (uint16_t*)alloc((size_t)3 * 4096 * 2);
    float*    sarr  = (float*)alloc((size_t)NN * 4);
    float*    rarr  = (float*)alloc((size_t)NN * 4);
    uint32_t* pairs = (uint32_t*)alloc((size_t)NBKT * CAP * 4);  // 12.8 MB padded
    uint16_t* GbA   = (uint16_t*)alloc((size_t)NN * HID * 2);    // 12.8 MB
    uint16_t* RbA   = (uint16_t*)alloc((size_t)NN * HID * 2);
    uint16_t* GbB   = (uint16_t*)alloc((size_t)NN * HID * 2);    // GbB/RbB contiguous
    uint16_t* RbB   = (uint16_t*)alloc((size_t)NN * HID * 2);
    (void)RbB;
    // bpairs (NBKT*CAP*8B = 25.6MB) aliases GbB+RbB (contiguous; dead before
    // mid layer 1 writes set B)
    int2*  bpairs = (int2*)GbB;

    // weight split + bucket cursor init (one launch)
    k_wsplit<<<(3 * 4096 + 255) / 256, 256, 0, stream>>>(
        Wrel_mid, Wroot_mid, WgH, WgL, WrH, WrL, bcur);

    // CSR build (padded buckets)
    k_bpart<<<NTILE, 256, 0, stream>>>(src, dstp, ew, bcur, bpairs);
    k_bcsr<<<NBKT, 256, 0, stream>>>(bcur, bpairs, offs, ends, pairs);

    // layer 0 (agg + transform + pre) -> G1,R1 (set A)
    k_l0pre<<<NN / 16, 256, 0, stream>>>(
        offs, ends, pairs, x, Wrel0, brel0, Wroot0,
        WgH, WgL, WrH, WrL, brel_mid, GbA, RbA);

    // mid layer 1: consume set A, produce set B (weights index 1)
    k_aggfused<false><<<NN / 16, 256, 0, stream>>>(
        offs, ends, pairs, GbA, RbA,
        WgH + 4096, WgL + 4096, WrH + 4096, WrL + 4096, brel_mid + HID,
        GbB, RbB, WrelL, WrootL, sarr, rarr);
    // mid layer 2: consume set B, produce set A (weights index 2)
    k_aggfused<false><<<NN / 16, 256, 0, stream>>>(
        offs, ends, pairs, GbB, RbB,
        WgH + 2 * 4096, WgL + 2 * 4096, WrH + 2 * 4096, WrL + 2 * 4096,
        brel_mid + 2 * HID, GbA, RbA, WrelL, WrootL, sarr, rarr);
    // mid layer 3 (LAST): consume set A, produce s/r scalars
    k_aggfused<true><<<NN / 16, 256, 0, stream>>>(
        offs, ends, pairs, GbA, RbA,
        WgH, WgL, WrH, WrL, brel_mid,
        GbB, RbB, WrelL, WrootL, sarr, rarr);

    // final edge pass on scalars
    k_last<<<(NN + 255) / 256, 256, 0, stream>>>(offs, ends, pairs, sarr, rarr, brelL, out);
}

// Round 19
// 325.333 us; speedup vs baseline: 1.3011x; 1.0071x over previous
//
#include <hip/hip_runtime.h>
#include <stdint.h>

// GraphConv x5 on MI355X — round 19.
// vs round 18 (327.6us): k_bpart scatters through an LDS counting sort of
// the 4096-edge tile (hist -> 512-wide ping-pong scan -> LDS scatter with
// per-slot global-adjust), then writes out linearly: consecutive LDS slots
// in a bucket run hit consecutive global addresses (~10x store coalescing
// vs per-lane scatter to ~16 segments each). Everything else unchanged.

#define NN 100000
#define NE 1600000
#define HID 64
#define NBKT 391            // ceil(NN/256), bucket = dst >> 8
#define CAP 8192            // padded bucket capacity (mean 4092, +64 sigma)
#define TILE 4096
#define EPT 16              // TILE / 256
#define NTILE ((NE + TILE - 1) / TILE)   // 391

typedef __attribute__((ext_vector_type(8))) short bf16x8;
typedef __attribute__((ext_vector_type(4))) float f32x4;

__device__ __forceinline__ uint32_t rne_bf16(float v) {
    uint32_t u = __float_as_uint(v);
    return (u + 0x7fffu + ((u >> 16) & 1u)) >> 16;
}

// ---------------- CSR build ----------------

// tile-local LDS counting sort + coalesced segment write-out
__global__ __launch_bounds__(256) void k_bpart(const int* __restrict__ src,
                                               const int* __restrict__ dst,
                                               const float* __restrict__ w,
                                               int* __restrict__ bcur,
                                               int2* __restrict__ bpairs) {
    __shared__ int  hcnt[NBKT];      // count, then cursor
    __shared__ int  hoff[NBKT];      // local exclusive offset
    __shared__ int  hadj[NBKT];      // global base - local offset
    __shared__ int  sc0[512];
    __shared__ int  sc1[512];
    __shared__ int2 sT[TILE];        // 32 KB staged tile (bucket-sorted)
    __shared__ int  sAdj[TILE];      // 16 KB per-slot global adjust
    int tile0 = blockIdx.x * TILE;
    int t = threadIdx.x;
    for (int i = t; i < NBKT; i += 256) hcnt[i] = 0;
    __syncthreads();

    int   pk[EPT];
    int   bk[EPT];
    float wv[EPT];
    #pragma unroll
    for (int k = 0; k < EPT; k++) {
        int e = tile0 + t + k * 256;
        if (e < NE) {
            int d = dst[e];
            int b = d >> 8;
            pk[k] = (src[e] << 8) | (d & 255);
            wv[k] = w[e];
            bk[k] = b;
            atomicAdd(&hcnt[b], 1);
        } else {
            bk[k] = -1;
        }
    }
    __syncthreads();

    // inclusive scan of hcnt over 512 (padded) with ping-pong buffers
    sc0[t]       = (t < NBKT) ? hcnt[t] : 0;
    sc0[t + 256] = (t + 256 < NBKT) ? hcnt[t + 256] : 0;
    __syncthreads();
    int* cur = sc0;
    int* oth = sc1;
    for (int off = 1; off < 512; off <<= 1) {
        int v0 = cur[t]       + ((t       >= off) ? cur[t - off]       : 0);
        int v1 = cur[t + 256] + ((t + 256 >= off) ? cur[t + 256 - off] : 0);
        oth[t] = v0;
        oth[t + 256] = v1;
        __syncthreads();
        int* tmp = cur; cur = oth; oth = tmp;
    }
    for (int i = t; i < NBKT; i += 256) {
        int c = hcnt[i];
        int excl = cur[i] - c;
        hoff[i] = excl;
        int gbase = c ? atomicAdd(&bcur[i], c) : 0;
        hadj[i] = gbase - excl;
        hcnt[i] = 0;                 // reuse as local cursor
    }
    __syncthreads();

    // scatter into LDS (bucket-sorted order)
    #pragma unroll
    for (int k = 0; k < EPT; k++) {
        if (bk[k] >= 0) {
            int b = bk[k];
            int pos = hoff[b] + atomicAdd(&hcnt[b], 1);
            sT[pos] = make_int2(pk[k], __float_as_int(wv[k]));
            sAdj[pos] = hadj[b];
        }
    }
    __syncthreads();

    // linear write-out: consecutive slots in a bucket run -> consecutive
    // global addresses (coalesced bursts)
    int n = NE - tile0; if (n > TILE) n = TILE;
    for (int j = t; j < n; j += 256)
        bpairs[sAdj[j] + j] = sT[j];
}

// one block per bucket: stage bucket in LDS, then LDS counting sort.
__global__ __launch_bounds__(256) void k_bcsr(const int* __restrict__ bcur,
                                              const int2* __restrict__ bpairs,
                                              int* __restrict__ offs,
                                              int* __restrict__ ends,
                                              uint32_t* __restrict__ pairs) {
    __shared__ int2 sE[CAP];        // 64 KB bucket stage
    __shared__ int cnt[256];
    __shared__ int scn[256];
    __shared__ int cur[256];
    int k = blockIdx.x, t = threadIdx.x;
    int base = k * CAP;
    int scnt = bcur[k] - base;
    cnt[t] = 0;
    __syncthreads();
    for (int j = t; j < scnt; j += 256) {
        int2 q = bpairs[base + j];
        sE[j] = q;
        atomicAdd(&cnt[q.x & 255], 1);
    }
    __syncthreads();
    int v = cnt[t], acc = v;
    scn[t] = v;
    __syncthreads();
    for (int off = 1; off < 256; off <<= 1) {
        int u = (t >= off) ? scn[t - off] : 0;
        __syncthreads();
        acc += u;
        scn[t] = acc;
        __syncthreads();
    }
    int excl = acc - v;
    cur[t] = excl;
    int d = (k << 8) + t;
    if (d < NN) {
        offs[d] = base + excl;
        ends[d] = base + excl + v;
    }
    __syncthreads();
    for (int j = t; j < scnt; j += 256) {
        int2 q = sE[j];
        int pos = base + atomicAdd(&cur[q.x & 255], 1);
        uint32_t wb = rne_bf16(__int_as_float(q.y)) & 0x7fffu;   // w >= 0
        pairs[pos] = (wb << 17) | (uint32_t)(q.x >> 8);
    }
}

// ---------------- weight hi/lo split (+ bucket cursor init) ----------------

__global__ __launch_bounds__(256) void k_wsplit(const float* __restrict__ Wrel_mid,
                                                const float* __restrict__ Wroot_mid,
                                                uint16_t* __restrict__ WgH,
                                                uint16_t* __restrict__ WgL,
                                                uint16_t* __restrict__ WrH,
                                                uint16_t* __restrict__ WrL,
                                                int* __restrict__ bcur) {
    int i = blockIdx.x * blockDim.x + threadIdx.x;
    if (i < NBKT) bcur[i] = i * CAP;
    if (i >= 3 * 4096) return;
    float a = Wrel_mid[i];
    uint32_t ah = rne_bf16(a);
    float al = a - __uint_as_float(ah << 16);
    WgH[i] = (uint16_t)ah;
    WgL[i] = (uint16_t)rne_bf16(al);
    float b = Wroot_mid[i];
    uint32_t bh = rne_bf16(b);
    float bl = b - __uint_as_float(bh << 16);
    WrH[i] = (uint16_t)bh;
    WrL[i] = (uint16_t)rne_bf16(bl);
}

// ---------------- shared epilogue: 16-node h (LDS) -> G,R via LDS tiles ----

__device__ __forceinline__ void mfma_epilogue(
        int lane, int w, const uint32_t* sH,
        const uint16_t* __restrict__ WgH, const uint16_t* __restrict__ WgL,
        const uint16_t* __restrict__ WrH, const uint16_t* __restrict__ WrL,
        const float* __restrict__ brel,
        uint16_t* sG, uint16_t* sR) {
    int row = lane & 15;
    int quad = lane >> 4;
    int kb = quad * 8;
    bf16x8 ah0 = *(const bf16x8*)&sH[row * 36 + quad * 4];
    bf16x8 ah1 = *(const bf16x8*)&sH[row * 36 + 16 + quad * 4];
    int oc = w * 16 + row;
    {
        bf16x8 bh0 = *(const bf16x8*)&WgH[oc * 64 + kb];
        bf16x8 bh1 = *(const bf16x8*)&WgH[oc * 64 + 32 + kb];
        bf16x8 bl0 = *(const bf16x8*)&WgL[oc * 64 + kb];
        bf16x8 bl1 = *(const bf16x8*)&WgL[oc * 64 + 32 + kb];
        f32x4 acc = {0.f, 0.f, 0.f, 0.f};
        acc = __builtin_amdgcn_mfma_f32_16x16x32_bf16(ah0, bh0, acc, 0, 0, 0);
        acc = __builtin_amdgcn_mfma_f32_16x16x32_bf16(ah1, bh1, acc, 0, 0, 0);
        acc = __builtin_amdgcn_mfma_f32_16x16x32_bf16(ah0, bl0, acc, 0, 0, 0);
        acc = __builtin_amdgcn_mfma_f32_16x16x32_bf16(ah1, bl1, acc, 0, 0, 0);
        #pragma unroll
        for (int r = 0; r < 4; r++)
            sG[(quad * 4 + r) * 68 + oc] = (uint16_t)rne_bf16(acc[r]);
    }
    {
        bf16x8 bh0 = *(const bf16x8*)&WrH[oc * 64 + kb];
        bf16x8 bh1 = *(const bf16x8*)&WrH[oc * 64 + 32 + kb];
        bf16x8 bl0 = *(const bf16x8*)&WrL[oc * 64 + kb];
        bf16x8 bl1 = *(const bf16x8*)&WrL[oc * 64 + 32 + kb];
        float bias = brel[oc];
        f32x4 acc = {bias, bias, bias, bias};
        acc = __builtin_amdgcn_mfma_f32_16x16x32_bf16(ah0, bh0, acc, 0, 0, 0);
        acc = __builtin_amdgcn_mfma_f32_16x16x32_bf16(ah1, bh1, acc, 0, 0, 0);
        acc = __builtin_amdgcn_mfma_f32_16x16x32_bf16(ah0, bl0, acc, 0, 0, 0);
        acc = __builtin_amdgcn_mfma_f32_16x16x32_bf16(ah1, bl1, acc, 0, 0, 0);
        #pragma unroll
        for (int r = 0; r < 4; r++)
            sR[(quad * 4 + r) * 68 + oc] = (uint16_t)rne_bf16(acc[r]);
    }
}

__device__ __forceinline__ void epilogue_writeout(
        int tid, int blk16, const uint16_t* sG, const uint16_t* sR,
        uint16_t* __restrict__ Gout, uint16_t* __restrict__ Rout) {
    const uint32_t* sGd = (const uint32_t*)sG;   // stride 34 dwords/node
    const uint32_t* sRd = (const uint32_t*)sR;
    uint32_t* Gd = (uint32_t*)Gout;
    uint32_t* Rd = (uint32_t*)Rout;
    #pragma unroll
    for (int it = 0; it < 2; it++) {
        int idx = it * 256 + tid;
        int nd = idx >> 5, col = idx & 31;
        Gd[(blk16 + nd) * 32 + col] = sGd[nd * 34 + col];
        Rd[(blk16 + nd) * 32 + col] = sRd[nd * 34 + col];
    }
}

// ---------------- layers ----------------

// layer 0 (fused): edge-parallel aggregation (all waves, shfl reduce), then
// h0 = relu(...) staged in LDS, MFMA epilogue -> G1,R1.
__global__ __launch_bounds__(256) void k_l0pre(
        const int* __restrict__ offs, const int* __restrict__ ends,
        const uint32_t* __restrict__ pairs, const float* __restrict__ x,
        const float* __restrict__ Wrel0, const float* __restrict__ brel0,
        const float* __restrict__ Wroot0,
        const uint16_t* __restrict__ WgH, const uint16_t* __restrict__ WgL,
        const uint16_t* __restrict__ WrH, const uint16_t* __restrict__ WrL,
        const float* __restrict__ brel,
        uint16_t* __restrict__ Gout, uint16_t* __restrict__ Rout) {
    __shared__ uint32_t sH[16 * 36];
    __shared__ uint16_t sG[16 * 68];
    __shared__ uint16_t sR[16 * 68];
    int c = threadIdx.x & 63;
    int w = threadIdx.x >> 6;
    int blk16 = blockIdx.x * 16;
    float agg[4];
    #pragma unroll
    for (int t = 0; t < 4; t++) {
        int node = blk16 + w * 4 + t;
        int b = offs[node], e = ends[node];
        float pp = 0.f;
        for (int j = b + c; j < e; j += 64) {
            uint32_t r = pairs[j];
            pp += __uint_as_float((r >> 17) << 16) * x[r & 0x1ffffu];
        }
        for (int o = 32; o > 0; o >>= 1) pp += __shfl_down(pp, o, 64);
        agg[t] = __shfl(pp, 0, 64);
    }
    float wr = Wrel0[c], br = brel0[c], wo = Wroot0[c];
    #pragma unroll
    for (int t = 0; t < 4; t++) {
        int node = blk16 + w * 4 + t;
        float v = agg[t] * wr + br + x[node] * wo;
        v = v > 0.f ? v : 0.f;
        uint32_t hb = rne_bf16(v);
        uint32_t pn = (uint32_t)__shfl_xor((int)hb, 1, 64);
        if (!(c & 1)) sH[(w * 4 + t) * 36 + (c >> 1)] = hb | (pn << 16);
    }
    __syncthreads();
    mfma_epilogue(c, w, sH, WgH, WgL, WrH, WrL, brel, sG, sR);
    __syncthreads();
    epilogue_writeout((int)threadIdx.x, blk16, sG, sR, Gout, Rout);
}

// Fused aggregation + pre-transform (round-14 validated: 16-deep load
// batches, 4 FMA chains/node, launch_bounds(256,4), Rb prefetch).
template <bool LAST>
__global__ __launch_bounds__(256, 4) void k_aggfused(
        const int* __restrict__ offs, const int* __restrict__ ends,
        const uint32_t* __restrict__ pairs,
        const uint16_t* __restrict__ Gb, const uint16_t* __restrict__ Rb,
        const uint16_t* __restrict__ WgH, const uint16_t* __restrict__ WgL,
        const uint16_t* __restrict__ WrH, const uint16_t* __restrict__ WrL,
        const float* __restrict__ brel,
        uint16_t* __restrict__ Gout, uint16_t* __restrict__ Rout,
        const float* __restrict__ WrelL, const float* __restrict__ WrootL,
        float* __restrict__ sarr, float* __restrict__ rarr) {
    __shared__ uint32_t sH[16 * 36];
    __shared__ uint16_t sG[16 * 68];
    __shared__ uint16_t sR[16 * 68];
    int c = threadIdx.x & 63;
    int w = threadIdx.x >> 6;
    int blk16 = blockIdx.x * 16;
    int n0 = blk16 + w * 4;
    int ov = 0;
    if (c < 4) ov = offs[n0 + c];
    else if (c == 4) ov = ends[n0 + 3];
    int bnd[5];
    bnd[0] = __builtin_amdgcn_readlane(ov, 0);
    bnd[1] = __builtin_amdgcn_readlane(ov, 1);
    bnd[2] = __builtin_amdgcn_readlane(ov, 2);
    bnd[3] = __builtin_amdgcn_readlane(ov, 3);
    bnd[4] = __builtin_amdgcn_readlane(ov, 4);

    // prefetch R rows (consumed only in the epilogue)
    uint32_t ur[4];
    #pragma unroll
    for (int t = 0; t < 4; t++) ur[t] = Rb[(n0 + t) * 64 + c];

    float acc[4][4];
    #pragma unroll
    for (int t = 0; t < 4; t++)
        #pragma unroll
        for (int q = 0; q < 4; q++) acc[t][q] = 0.f;

    for (int cb = bnd[0]; cb < bnd[4]; cb += 64) {
        int n = bnd[4] - cb; if (n > 64) n = 64;
        uint32_t p = (c < n) ? pairs[cb + c] : 0u;
        #pragma unroll
        for (int t = 0; t < 4; t++) {
            int lo = bnd[t]     > cb     ? bnd[t]     : cb;
            int hi = bnd[t + 1] < cb + n ? bnd[t + 1] : cb + n;
            int j = lo;
            for (; j + 16 <= hi; j += 16) {
                int jj = j - cb;
                uint32_t rr[16], uu[16];
                #pragma unroll
                for (int q = 0; q < 16; q++)
                    rr[q] = __builtin_amdgcn_readlane(p, jj + q);
                #pragma unroll
                for (int q = 0; q < 16; q++)
                    uu[q] = Gb[(rr[q] & 0x1ffffu) * 64 + c];
                #pragma unroll
                for (int q = 0; q < 16; q++)
                    acc[t][q & 3] += __uint_as_float((rr[q] >> 17) << 16)
                                   * __uint_as_float(uu[q] << 16);
            }
            for (; j + 8 <= hi; j += 8) {
                int jj = j - cb;
                uint32_t rr[8], uu[8];
                #pragma unroll
                for (int q = 0; q < 8; q++)
                    rr[q] = __builtin_amdgcn_readlane(p, jj + q);
                #pragma unroll
                for (int q = 0; q < 8; q++)
                    uu[q] = Gb[(rr[q] & 0x1ffffu) * 64 + c];
                #pragma unroll
                for (int q = 0; q < 8; q++)
                    acc[t][q & 3] += __uint_as_float((rr[q] >> 17) << 16)
                                   * __uint_as_float(uu[q] << 16);
            }
            for (; j + 4 <= hi; j += 4) {
                int jj = j - cb;
                uint32_t rr[4], uu[4];
                #pragma unroll
                for (int q = 0; q < 4; q++)
                    rr[q] = __builtin_amdgcn_readlane(p, jj + q);
                #pragma unroll
                for (int q = 0; q < 4; q++)
                    uu[q] = Gb[(rr[q] & 0x1ffffu) * 64 + c];
                #pragma unroll
                for (int q = 0; q < 4; q++)
                    acc[t][q] += __uint_as_float((rr[q] >> 17) << 16)
                               * __uint_as_float(uu[q] << 16);
            }
            for (; j < hi; j++) {
                int jj = j - cb;
                uint32_t r = __builtin_amdgcn_readlane(p, jj);
                uint32_t u = Gb[(r & 0x1ffffu) * 64 + c];
                acc[t][0] += __uint_as_float((r >> 17) << 16)
                           * __uint_as_float(u << 16);
            }
        }
    }
    #pragma unroll
    for (int t = 0; t < 4; t++) {
        float v = (acc[t][0] + acc[t][1]) + (acc[t][2] + acc[t][3])
                + __uint_as_float(ur[t] << 16);
        v = v > 0.f ? v : 0.f;
        if (!LAST) {
            uint32_t hb = rne_bf16(v);
            uint32_t pn = (uint32_t)__shfl_xor((int)hb, 1, 64);
            if (!(c & 1)) sH[(w * 4 + t) * 36 + (c >> 1)] = hb | (pn << 16);
        } else {
            float a = v * WrelL[c];
            float r = v * WrootL[c];
            for (int o = 32; o > 0; o >>= 1) {
                a += __shfl_down(a, o, 64);
                r += __shfl_down(r, o, 64);
            }
            if (c == 0) { sarr[n0 + t] = a; rarr[n0 + t] = r; }
        }
    }
    if (!LAST) {
        __syncthreads();
        mfma_epilogue(c, w, sH, WgH, WgL, WrH, WrL, brel, sG, sR);
        __syncthreads();
        epilogue_writeout((int)threadIdx.x, blk16, sG, sR, Gout, Rout);
    }
}

__global__ void k_last(const int* __restrict__ offs, const int* __restrict__ ends,
                       const uint32_t* __restrict__ pairs,
                       const float* __restrict__ sarr, const float* __restrict__ rarr,
                       const float* __restrict__ brelL, float* __restrict__ out) {
    int i = blockIdx.x * blockDim.x + threadIdx.x;
    if (i >= NN) return;
    float a0 = rarr[i] + brelL[0], a1 = 0.f;
    int b = offs[i], e = ends[i];
    int j = b;
    for (; j + 2 <= e; j += 2) {
        uint32_t r0 = pairs[j], r1 = pairs[j + 1];
        a0 += __uint_as_float((r0 >> 17) << 16) * sarr[r0 & 0x1ffffu];
        a1 += __uint_as_float((r1 >> 17) << 16) * sarr[r1 & 0x1ffffu];
    }
    for (; j < e; j++) {
        uint32_t r = pairs[j];
        a0 += __uint_as_float((r >> 17) << 16) * sarr[r & 0x1ffffu];
    }
    out[i] = a0 + a1;
}

extern "C" void kernel_launch(void* const* d_in, const int* in_sizes, int n_in,
                              void* d_out, int out_size, void* d_ws, size_t ws_size,
                              hipStream_t stream) {
    const float* x        = (const float*)d_in[0];
    const int*   ei       = (const int*)d_in[1];
    const float* ew       = (const float*)d_in[2];
    const float* Wrel0    = (const float*)d_in[3];
    const float* brel0    = (const float*)d_in[4];
    const float* Wroot0   = (const float*)d_in[5];
    const float* Wrel_mid = (const float*)d_in[6];
    const float* brel_mid = (const float*)d_in[7];
    const float* Wroot_mid= (const float*)d_in[8];
    const float* WrelL    = (const float*)d_in[9];
    const float* brelL    = (const float*)d_in[10];
    const float* WrootL   = (const float*)d_in[11];
    float* out = (float*)d_out;

    const int* src  = ei;
    const int* dstp = ei + NE;

    char* w = (char*)d_ws;
    size_t o = 0;
    auto alloc = [&](size_t b) -> void* {
        void* r = (void*)(w + o);
        o += (b + 255) & ~(size_t)255;
        return r;
    };
    int*      offs  = (int*)alloc((size_t)NN * 4);
    int*      ends  = (int*)alloc((size_t)NN * 4);
    int*      bcur  = (int*)alloc((size_t)NBKT * 4);
    uint16_t* WgH   = (uint16_t*)alloc((size_t)3 * 4096 * 2);
    uint16_t* WgL   = (uint16_t*)alloc((size_t)3 * 4096 * 2);
    uint16_t* WrH   = (uint16_t*)alloc((size_t)3 * 4096 * 2);
    uint16_t* WrL   = (uint16_t*)alloc((size_t)3 * 4096 * 2);
    float*    sarr  = (float*)alloc((size_t)NN * 4);
    float*    rarr  = (float*)alloc((size_t)NN * 4);
    uint32_t* pairs = (uint32_t*)alloc((size_t)NBKT * CAP * 4);  // 12.8 MB padded
    uint16_t* GbA   = (uint16_t*)alloc((size_t)NN * HID * 2);    // 12.8 MB
    uint16_t* RbA   = (uint16_t*)alloc((size_t)NN * HID * 2);
    uint16_t* GbB   = (uint16_t*)alloc((size_t)NN * HID * 2);    // GbB/RbB contiguous
    uint16_t* RbB   = (uint16_t*)alloc((size_t)NN * HID * 2);
    (void)RbB;
    // bpairs (NBKT*CAP*8B = 25.6MB) aliases GbB+RbB (contiguous; dead before
    // mid layer 1 writes set B)
    int2*  bpairs = (int2*)GbB;

    // weight split + bucket cursor init (one launch)
    k_wsplit<<<(3 * 4096 + 255) / 256, 256, 0, stream>>>(
        Wrel_mid, Wroot_mid, WgH, WgL, WrH, WrL, bcur);

    // CSR build (padded buckets)
    k_bpart<<<NTILE, 256, 0, stream>>>(src, dstp, ew, bcur, bpairs);
    k_bcsr<<<NBKT, 256, 0, stream>>>(bcur, bpairs, offs, ends, pairs);

    // layer 0 (agg + transform + pre) -> G1,R1 (set A)
    k_l0pre<<<NN / 16, 256, 0, stream>>>(
        offs, ends, pairs, x, Wrel0, brel0, Wroot0,
        WgH, WgL, WrH, WrL, brel_mid, GbA, RbA);

    // mid layer 1: consume set A, produce set B (weights index 1)
    k_aggfused<false><<<NN / 16, 256, 0, stream>>>(
        offs, ends, pairs, GbA, RbA,
        WgH + 4096, WgL + 4096, WrH + 4096, WrL + 4096, brel_mid + HID,
        GbB, RbB, WrelL, WrootL, sarr, rarr);
    // mid layer 2: consume set B, produce set A (weights index 2)
    k_aggfused<false><<<NN / 16, 256, 0, stream>>>(
        offs, ends, pairs, GbB, RbB,
        WgH + 2 * 4096, WgL + 2 * 4096, WrH + 2 * 4096, WrL + 2 * 4096,
        brel_mid + 2 * HID, GbA, RbA, WrelL, WrootL, sarr, rarr);
    // mid layer 3 (LAST): consume set A, produce s/r scalars
    k_aggfused<true><<<NN / 16, 256, 0, stream>>>(
        offs, ends, pairs, GbA, RbA,
        WgH, WgL, WrH, WrL, brel_mid,
        GbB, RbB, WrelL, WrootL, sarr, rarr);

    // final edge pass on scalars
    k_last<<<(NN + 255) / 256, 256, 0, stream>>>(offs, ends, pairs, sarr, rarr, brelL, out);
}